// Round 7
// baseline (1610.958 us; speedup 1.0000x reference)
//
#include <hip/hip_runtime.h>
#include <stdint.h>
#include <stddef.h>

#define NEGF (-1.0e30f)

typedef __attribute__((ext_vector_type(2))) _Float16 half2_t;
typedef __attribute__((ext_vector_type(8))) _Float16 f16x8;
typedef __attribute__((ext_vector_type(4))) float f32x4;
typedef __attribute__((ext_vector_type(4))) uint32_t u32x4;

constexpr int Bn = 32;
constexpr int Tn = 2000;
constexpr int Cn = 256;
constexpr int Un = 200;
constexpr int Sn = 2 * Un + 1;  // 401 extended states
constexpr float Kn = 4096.0f;   // den normalization target
constexpr int NBD = 2;          // den blocks
constexpr int BPB = 16;         // batches per den block

// f16 pair dot with fp32 accumulate: c += a.x*b.x + a.y*b.y
__device__ __forceinline__ float fdot2f(uint32_t a, uint32_t b, float c) {
  half2_t ha = __builtin_bit_cast(half2_t, a);
  half2_t hb = __builtin_bit_cast(half2_t, b);
#if __has_builtin(__builtin_amdgcn_fdot2)
  return __builtin_amdgcn_fdot2(ha, hb, c, false);
#else
  return c + (float)ha.x * (float)hb.x + (float)ha.y * (float)hb.y;
#endif
}

__device__ __forceinline__ uint32_t packe(float a, float b) {
  half2_t h;
  h.x = (_Float16)a;
  h.y = (_Float16)b;
  return __builtin_bit_cast(uint32_t, h);
}

__device__ __forceinline__ float lse3(float a, float b, float c) {
  float m = fmaxf(fmaxf(a, b), c);
  return m + __logf(__expf(a - m) + __expf(b - m) + __expf(c - m));
}

__device__ __forceinline__ int clampi(int v, int lo, int hi) {
  return v < lo ? lo : (v > hi ? hi : v);
}

__device__ __forceinline__ f32x4 exp4(f32x4 v) {
  f32x4 r;
  r[0] = __expf(v[0]);
  r[1] = __expf(v[1]);
  r[2] = __expf(v[2]);
  r[3] = __expf(v[3]);
  return r;
}

// Barrier WITHOUT the vmcnt(0) drain __syncthreads() emits: only LDS
// (lgkmcnt) must drain for cross-wave ds_write visibility; the compiler
// still inserts counted vmcnt(N) before each prefetch USE.
__device__ __forceinline__ void barrier_nodrain() {
  asm volatile("s_waitcnt lgkmcnt(0)" ::: "memory");
  __builtin_amdgcn_s_barrier();
  asm volatile("" ::: "memory");
}

// ============================================================================
// ROUND-9: MFMA den, serial spine removed. R6 measured ~1836 cyc/step: the
// Z-chain (f16 tree -> fdot2 -> 2x shfl_xor DS-ops, ~300 cyc serial, gating
// the epilogue) + 2 barriers/step + tail-issued exp/loads were all exposed at
// 1 wave/SIMD. Changes (den only, R6 otherwise verbatim):
//  1. Z via ones-A MFMA (2x 4-deep chains on the matrix pipe, concurrent
//     with acc; Z lands lane-local in f32). Deletes tree+fdot2+shfls.
//  2. Double-buffered Abuf -> ONE barrier/step. Freeze under dbuf: lane
//     re-writes its remembered prev_pk (write slots are loop-invariant);
//     also replaces the separate t=0 init block.
//  3. Emission prefetch issued at the top of the step (hides under MFMA).
// ============================================================================

__global__ __launch_bounds__(256)
__attribute__((amdgpu_waves_per_eu(1, 1)))
void fwd_kernel(
    const float* __restrict__ logp, const int* __restrict__ targets,
    const int* __restrict__ in_lens, const int* __restrict__ tgt_lens,
    const float* __restrict__ trans, const float* __restrict__ start,
    float* __restrict__ ws) {
  const int tid = threadIdx.x;
  const int bid = blockIdx.x;

  if (bid < NBD) {
    // ======================= MFMA denominator =======================
    __shared__ __align__(16) char Abuf[2 * 16 * 512];  // alpha f16, dbuf, swizzled
    __shared__ float stage[32 * 258];                  // E-init staging

    const int lane = tid & 63;
    const int w = tid >> 6;    // wave 0..3, owns j in [64w, 64w+64)
    const int br = lane & 15;  // batch row this lane owns (D col)
    const int g = lane >> 4;   // k-quarter / j-subgroup
    const int gb = bid * BPB + br;
    const int jbase = 64 * w;

    const int Lv = clampi(in_lens[gb], Sn, Tn);
    int Lblk = Lv;  // block-uniform max L (barrier trip count)
#pragma unroll
    for (int off = 1; off < 16; off <<= 1) {
      const int o = __shfl_xor(Lblk, off, 64);
      Lblk = Lblk > o ? Lblk : o;
    }

    // ---- E^T fragments (static): E[mt][kt], lane l holds rows j=jbase+16mt+br
    //      k = 32kt + 8g + jj. Built via coalesced chunk staging in LDS. ----
    f16x8 E[4][8];
#pragma unroll
    for (int kt = 0; kt < 8; ++kt) {
      const float* src = trans + (size_t)(32 * kt) * Cn;  // rows [32kt,32kt+32)
#pragma unroll
      for (int jj = 0; jj < 8; ++jj) {
        const int i4 = tid + jj * 256;  // float4 index in chunk
        const float4 v = *(const float4*)(src + 4 * (size_t)i4);
        const int r = i4 >> 6, c = (i4 & 63) * 4;
        float* dst = stage + r * 258 + c;
        *(float2*)(dst) = make_float2(v.x, v.y);
        *(float2*)(dst + 2) = make_float2(v.z, v.w);
      }
      __syncthreads();
#pragma unroll
      for (int mt = 0; mt < 4; ++mt) {
        const int j = jbase + 16 * mt + br;
        f16x8 e;
#pragma unroll
        for (int jj = 0; jj < 8; ++jj)
          e[jj] = (_Float16)__expf(stage[(8 * g + jj) * 258 + j]);
        E[mt][kt] = e;
      }
      __syncthreads();
    }

    // ---- loop-invariant LDS addresses (conflict-free by swizzle; R6 layout) ----
    const char* rdp[8];
#pragma unroll
    for (int kt = 0; kt < 8; ++kt)
      rdp[kt] = Abuf + br * 512 + ((64 * kt + 16 * g) ^ ((br & 7) << 4));
    char* wrp[4];
#pragma unroll
    for (int mt = 0; mt < 4; ++mt)
      wrp[mt] = Abuf + br * 512 + ((2 * (jbase + 16 * mt + 4 * g)) ^ ((br & 7) << 4));

    // ---- t = 0: this lane OWNS its 16 write-slot j's. alpha0 = K*exp(start+lp0)
    //      computed locally, written to buf0, remembered in prev (freeze source).
    const float* lpl = logp + (size_t)gb * Tn * Cn + (jbase + 4 * g);
    f32x4 P0[4], P1[4];
    uint2 prev[4];
#pragma unroll
    for (int mt = 0; mt < 4; ++mt) {
      const f32x4 F0 = *(const f32x4*)(lpl + 16 * mt);                   // frame 0
      const f32x4 st = *(const f32x4*)(start + jbase + 4 * g + 16 * mt);
      const float v0 = Kn * __expf(st[0] + F0[0]);
      const float v1 = Kn * __expf(st[1] + F0[1]);
      const float v2 = Kn * __expf(st[2] + F0[2]);
      const float v3 = Kn * __expf(st[3] + F0[3]);
      uint2 pk;
      pk.x = packe(v0, v1);
      pk.y = packe(v2, v3);
      prev[mt] = pk;
      *(uint2*)(wrp[mt]) = pk;  // buffer 0
      P0[mt] = exp4(*(const f32x4*)(lpl + (size_t)1 * Cn + 16 * mt));    // frame 1, exp'd
      P1[mt] = *(const f32x4*)(lpl + (size_t)2 * Cn + 16 * mt);          // frame 2, raw
    }
    float G = -__logf(Kn);
    __syncthreads();

    const _Float16 ONE1 = (_Float16)1.f;
    const f16x8 ONES8 = {ONE1, ONE1, ONE1, ONE1, ONE1, ONE1, ONE1, ONE1};

    for (int t = 1; t < Lblk; ++t) {
      const int ro = ((t - 1) & 1) * 8192, wo = (t & 1) * 8192;

      // B-fragments from the read buffer
      f16x8 Bf[8];
#pragma unroll
      for (int kt = 0; kt < 8; ++kt) Bf[kt] = *(const f16x8*)(rdp[kt] + ro);

      // issue next emission frame NOW (latency hides under the MFMA phase)
      const int tpre = (t + 2 < Lblk) ? t + 2 : Lblk - 1;
      f32x4 Pn[4];
#pragma unroll
      for (int mt = 0; mt < 4; ++mt)
        Pn[mt] = *(const f32x4*)(lpl + (size_t)tpre * Cn + 16 * mt);

      // Z_b = sum_k alpha[b][k] via ones-A MFMA: two 4-deep chains on the
      // matrix pipe, concurrent with acc below; lane-local f32 result.
      f32x4 Za = {0.f, 0.f, 0.f, 0.f}, Zb = {0.f, 0.f, 0.f, 0.f};
#pragma unroll
      for (int kt = 0; kt < 4; ++kt)
        Za = __builtin_amdgcn_mfma_f32_16x16x32_f16(ONES8, Bf[kt], Za, 0, 0, 0);
#pragma unroll
      for (int kt = 4; kt < 8; ++kt)
        Zb = __builtin_amdgcn_mfma_f32_16x16x32_f16(ONES8, Bf[kt], Zb, 0, 0, 0);

      // D[j][b] += E^T * alpha: 4 independent 8-deep MFMA chains
      f32x4 acc[4];
#pragma unroll
      for (int mt = 0; mt < 4; ++mt) {
        f32x4 a = {0.f, 0.f, 0.f, 0.f};
#pragma unroll
        for (int kt = 0; kt < 8; ++kt)
          a = __builtin_amdgcn_mfma_f32_16x16x32_f16(E[mt][kt], Bf[kt], a, 0, 0, 0);
        acc[mt] = a;
      }

      const float invZ = Kn * __frcp_rn(Za[0] + Zb[0]);
      if (t < Lv) G -= __logf(invZ);

      // epilogue: write to the OTHER buffer; frozen batches re-write prev
      // (their row stays at the freeze value in both buffers).
      uint2 pk[4];
      if (t < Lv) {
#pragma unroll
        for (int mt = 0; mt < 4; ++mt) {
          const float s0 = acc[mt][0] * P0[mt][0] * invZ;
          const float s1 = acc[mt][1] * P0[mt][1] * invZ;
          const float s2 = acc[mt][2] * P0[mt][2] * invZ;
          const float s3 = acc[mt][3] * P0[mt][3] * invZ;
          pk[mt].x = packe(s0, s1);
          pk[mt].y = packe(s2, s3);
        }
      } else {
#pragma unroll
        for (int mt = 0; mt < 4; ++mt) pk[mt] = prev[mt];
      }
#pragma unroll
      for (int mt = 0; mt < 4; ++mt) {
        *(uint2*)(wrp[mt] + wo) = pk[mt];
        prev[mt] = pk[mt];
      }

      // shift emission window (exp off the alpha critical path)
#pragma unroll
      for (int mt = 0; mt < 4; ++mt) {
        P0[mt] = exp4(P1[mt]);
        P1[mt] = Pn[mt];
      }

      barrier_nodrain();  // single barrier: writes to buf^1 visible next step
    }

    // den[b] = G[b] + log(sum_k alpha_final[b][k])  (runs once; R6 path)
    {
      const int rf = ((Lblk - 1) & 1) * 8192;
      f16x8 Bf[8];
#pragma unroll
      for (int kt = 0; kt < 8; ++kt) Bf[kt] = *(const f16x8*)(rdp[kt] + rf);
      half2_t zp = {(_Float16)0.f, (_Float16)0.f};
#pragma unroll
      for (int kt = 0; kt < 8; ++kt) {
        const u32x4 q = __builtin_bit_cast(u32x4, Bf[kt]);
        zp = zp + ((__builtin_bit_cast(half2_t, q.x) + __builtin_bit_cast(half2_t, q.y)) +
                   (__builtin_bit_cast(half2_t, q.z) + __builtin_bit_cast(half2_t, q.w)));
      }
      const uint32_t ONE2 = 0x3C003C00u;  // f16 (1.0, 1.0)
      float rs = fdot2f(ONE2, __builtin_bit_cast(uint32_t, zp), 0.f);
      rs += __shfl_xor(rs, 16, 64);
      rs += __shfl_xor(rs, 32, 64);
      if (tid < 16) ws[Bn + bid * BPB + tid] = G + __logf(rs);
    }
  } else {
    // ============== CTC numerator forward (log domain, R1-verbatim) ==============
    const int b = bid - NBD;
    const int L = clampi(in_lens[b], Sn, Tn);
    const int tl = clampi(tgt_lens[b], 1, Un);

    __shared__ float abuf[2][Sn + 3];  // +2 front pad (NEG), states at [s+2]
    const float* lpb = logp + (size_t)b * Tn * Cn;
    const int* tgtb = targets + b * Un;

    const int s1 = tid;        // states 0..255
    const int s2 = tid + 256;  // states 256..400 (valid if < Sn)
    int e1 = 0, e2 = 0;
    bool k1 = false, k2 = false;
    if (s1 & 1) {
      const int uu = (s1 - 1) >> 1;
      e1 = clampi(tgtb[uu], 1, Cn - 1);
      if (uu > 0) k1 = (e1 != clampi(tgtb[uu - 1], 1, Cn - 1));
    }
    if ((s2 < Sn) && (s2 & 1)) {
      const int uu = (s2 - 1) >> 1;
      e2 = clampi(tgtb[uu], 1, Cn - 1);
      k2 = (e2 != clampi(tgtb[uu - 1], 1, Cn - 1));  // uu >= 127 > 0 here
    }

    // t = 0 init
    abuf[0][s1 + 2] = (s1 == 0) ? lpb[0] : (s1 == 1 ? lpb[e1] : NEGF);
    if (s2 < Sn) abuf[0][s2 + 2] = NEGF;
    if (tid < 2) { abuf[0][tid] = NEGF; abuf[1][tid] = NEGF; }
    // 2-deep emission prefetch (addresses t-invariant per thread).
    float pe1_0 = lpb[Cn + e1];              // t = 1
    float pe2_0 = lpb[Cn + e2];
    float pe1_1 = lpb[(size_t)2 * Cn + e1];  // t = 2 (L >= 401)
    float pe2_1 = lpb[(size_t)2 * Cn + e2];
    __syncthreads();

    int cur = 0;
    for (int t = 1; t < L; ++t) {
      const float em1 = pe1_0, em2 = pe2_0;
      pe1_0 = pe1_1;
      pe2_0 = pe2_1;
      const int tpre = (t + 2 < L) ? t + 2 : L - 1;
      pe1_1 = lpb[(size_t)tpre * Cn + e1];
      pe2_1 = lpb[(size_t)tpre * Cn + e2];
      const float* A = abuf[cur];
      float* Bv = abuf[cur ^ 1];
      {
        const float x = A[s1 + 2], y = A[s1 + 1];
        const float z = k1 ? A[s1] : NEGF;
        Bv[s1 + 2] = lse3(x, y, z) + em1;
      }
      if (s2 < Sn) {
        const float x = A[s2 + 2], y = A[s2 + 1];
        const float z = k2 ? A[s2] : NEGF;
        Bv[s2 + 2] = lse3(x, y, z) + em2;
      }
      barrier_nodrain();
      cur ^= 1;
    }
    if (tid == 0) {
      const int l = 2 * tl;
      const float x = abuf[cur][l + 2], y = abuf[cur][l + 1];
      const float m = fmaxf(x, y);
      ws[b] = m + __logf(__expf(x - m) + __expf(y - m));
    }
  }
}

__global__ void finalize_kernel(const float* __restrict__ ws,
                                float* __restrict__ out) {
  const int tid = threadIdx.x;  // 64 threads, one wave
  float tot = 0.f, cnt = 0.f;
  if (tid < Bn) {
    const float tv = ws[tid] - ws[Bn + tid];  // num - DEN_SCALE*den
    const bool valid = tv > 0.5f * NEGF;
    tot = valid ? tv : 0.f;
    cnt = valid ? 1.f : 0.f;
  }
#pragma unroll
  for (int off = 32; off >= 1; off >>= 1) {
    tot += __shfl_xor(tot, off, 64);
    cnt += __shfl_xor(cnt, off, 64);
  }
  if (tid == 0) out[0] = -tot / fmaxf(cnt, 1.f);
}

extern "C" void kernel_launch(void* const* d_in, const int* in_sizes, int n_in,
                              void* d_out, int out_size, void* d_ws, size_t ws_size,
                              hipStream_t stream) {
  const float* logp = (const float*)d_in[0];
  const int* targets = (const int*)d_in[1];
  const int* in_lens = (const int*)d_in[2];
  const int* tgt_lens = (const int*)d_in[3];
  const float* trans = (const float*)d_in[4];
  const float* start = (const float*)d_in[5];
  float* ws = (float*)d_ws;
  float* out = (float*)d_out;
  (void)in_sizes; (void)n_in; (void)out_size; (void)ws_size;

  fwd_kernel<<<dim3(NBD + Bn), dim3(256), 0, stream>>>(
      logp, targets, in_lens, tgt_lens, trans, start, ws);
  finalize_kernel<<<dim3(1), dim3(64), 0, stream>>>(ws, out);
}

// Round 8
// 1396.077 us; speedup vs baseline: 1.1539x; 1.1539x over previous
//
#include <hip/hip_runtime.h>
#include <stdint.h>
#include <stddef.h>

#define NEGF (-1.0e30f)

typedef __attribute__((ext_vector_type(2))) _Float16 half2_t;
typedef uint32_t u32x16 __attribute__((ext_vector_type(16)));

constexpr int Bn = 32;
constexpr int Tn = 2000;
constexpr int Cn = 256;
constexpr int Un = 200;
constexpr int Sn = 2 * Un + 1;  // 401 extended states
constexpr float Kn = 4096.0f;   // den normalization target

// f16 pair dot with fp32 accumulate: c += a.x*b.x + a.y*b.y
__device__ __forceinline__ float fdot2f(uint32_t a, uint32_t b, float c) {
  half2_t ha = __builtin_bit_cast(half2_t, a);
  half2_t hb = __builtin_bit_cast(half2_t, b);
#if __has_builtin(__builtin_amdgcn_fdot2)
  return __builtin_amdgcn_fdot2(ha, hb, c, false);
#else
  return c + (float)ha.x * (float)hb.x + (float)ha.y * (float)hb.y;
#endif
}

template <int CTRL>
__device__ __forceinline__ float dppf(float x) {
#if __has_builtin(__builtin_amdgcn_update_dpp)
  int xi = __builtin_bit_cast(int, x);
  int y = __builtin_amdgcn_update_dpp(0, xi, CTRL, 0xF, 0xF, false);
  return __builtin_bit_cast(float, y);
#else
  return x;
#endif
}
#define dpp_x1(v) dppf<0xB1>(v)   // quad_perm(1,0,3,2): lane ^ 1
#define dpp_x2(v) dppf<0x4E>(v)   // quad_perm(2,3,0,1): lane ^ 2
#define dpp_x7(v) dppf<0x141>(v)  // row_half_mirror:    lane ^ 7

__device__ __forceinline__ uint32_t packe(float a, float b) {
  half2_t h;
  h.x = (_Float16)a;
  h.y = (_Float16)b;
  return __builtin_bit_cast(uint32_t, h);
}

__device__ __forceinline__ float lse3(float a, float b, float c) {
  float m = fmaxf(fmaxf(a, b), c);
  return m + __logf(__expf(a - m) + __expf(b - m) + __expf(c - m));
}

__device__ __forceinline__ int clampi(int v, int lo, int hi) {
  return v < lo ? lo : (v > hi ? hi : v);
}

// Barrier WITHOUT the vmcnt(0) drain __syncthreads() emits: only LDS
// (lgkmcnt) must drain for cross-wave ds_write visibility; the compiler
// still inserts counted vmcnt(N) before each prefetch USE.
__device__ __forceinline__ void barrier_nodrain() {
  asm volatile("s_waitcnt lgkmcnt(0)" ::: "memory");
  __builtin_amdgcn_s_barrier();
  asm volatile("" ::: "memory");
}

// ============================================================================
// ROUND-10: den+num co-residency. The MFMA den (R6/R7, ~1530-1620us) is
// abandoned: latency-bound at ~1950 cyc/step on 2 CUs, worse than the fdot2
// den (990us standalone, R4). Key insight from R1/R2/R4: den's 1188 cyc/step
// = ~460 issue + ~700 exposed latency, and SAME-code extra waves don't hide
// it (R2: lockstep barrier -> co-stall at identical phase points). num is a
// DIFFERENT instruction stream with the same step/barrier structure and the
// same per-batch L. Fuse: 32 blocks x 512 thr; tid<256 = R1-den verbatim,
// tid>=256 = R1-num verbatim; shared per-step barrier. Each SIMD gets 1 den
// wave + 1 num wave; den's post-barrier ds_read/DPP-reduce bubbles fill with
// num's lse3 work and vice versa. Bonus: 2-wave/SIMD VGPR budget (256) lets
// E live fully in VGPRs (R1's VGPR_Count=132 implied AGPR parking + staging).
// Barrier discipline: identical trip count (same L), barrier at block scope,
// finales share one __syncthreads.
// ============================================================================

__global__ __launch_bounds__(512)
__attribute__((amdgpu_waves_per_eu(2, 2)))
void fwd_kernel(
    const float* __restrict__ logp, const int* __restrict__ targets,
    const int* __restrict__ in_lens, const int* __restrict__ tgt_lens,
    const float* __restrict__ trans, const float* __restrict__ start,
    float* __restrict__ ws) {
  const int tid = threadIdx.x;
  const int b = blockIdx.x;  // one batch per block: den half + num half
  const int L = clampi(in_lens[b], Sn, Tn);
  const bool isden = tid < 256;

  // ---- shared LDS (both halves) ----
  __shared__ __align__(16) char eaLDS[2 * 8 * 80];  // den alpha, 80B-stride chunks
  __shared__ float sred[4];
  __shared__ float abuf[2][Sn + 3];  // num alpha, +2 front pad

  const float* lpb = logp + (size_t)b * Tn * Cn;

  // ================= per-half persistent state =================
  // den
  u32x16 E0, E1, E2, E3, E4, E5, E6, E7;
  float G = 0.f, lp0 = 0.f, lp1 = 0.f;
  const char* rbase0 = nullptr;
  char* wptr0 = nullptr;
  int dq = 0;
  // num
  int e1 = 0, e2 = 0;
  bool k1 = false, k2 = false;
  float pe1_0 = 0.f, pe2_0 = 0.f, pe1_1 = 0.f, pe2_1 = 0.f;
  int s2v = 0;
  int cur = 0;

  if (isden) {
    // ============ den init (R1-verbatim, 32i x 8col tile) ============
    const int q = tid & 7;
    const int u = tid >> 3;
    const int jw = u + 32 * q;  // column this lane owns after the reduce
    dq = q;

    const float* trow = trans;
#define EP(c, m) packe(__expf(trow[(32 * q + 2 * (m)) * Cn + (c)]), \
                       __expf(trow[(32 * q + 2 * (m) + 1) * Cn + (c)]))
#define MKCOL(c)                                                          \
  (u32x16){EP(c, 0),  EP(c, 1),  EP(c, 2),  EP(c, 3),  EP(c, 4),          \
           EP(c, 5),  EP(c, 6),  EP(c, 7),  EP(c, 8),  EP(c, 9),          \
           EP(c, 10), EP(c, 11), EP(c, 12), EP(c, 13), EP(c, 14), EP(c, 15)}
    E0 = MKCOL(u + 0);
    E1 = MKCOL(u + 32);
    E2 = MKCOL(u + 64);
    E3 = MKCOL(u + 96);
    E4 = MKCOL(u + 128);
    E5 = MKCOL(u + 160);
    E6 = MKCOL(u + 192);
    E7 = MKCOL(u + 224);
#undef MKCOL
#undef EP

    rbase0 = eaLDS + 80 * q;
    wptr0 = eaLDS + 80 * q + 2 * u;

    // t = 0: stored = K * exp(start + lp0); G carries the log scale.
    G = -__logf(Kn);
    *(_Float16*)(wptr0) = (_Float16)(Kn * __expf(start[jw] + lpb[jw]));
    lp0 = lpb[Cn + jw];              // t = 1
    lp1 = lpb[(size_t)2 * Cn + jw];  // t = 2 (L >= Sn = 401)
  } else {
    // ============ num init (R1-verbatim, 2 states/thread) ============
    const int nt = tid - 256;
    const int* tgtb = targets + b * Un;
    const int s1 = nt;        // states 0..255
    s2v = nt + 256;           // states 256..400 (valid if < Sn)
    if (s1 & 1) {
      const int uu = (s1 - 1) >> 1;
      e1 = clampi(tgtb[uu], 1, Cn - 1);
      if (uu > 0) k1 = (e1 != clampi(tgtb[uu - 1], 1, Cn - 1));
    }
    if ((s2v < Sn) && (s2v & 1)) {
      const int uu = (s2v - 1) >> 1;
      e2 = clampi(tgtb[uu], 1, Cn - 1);
      k2 = (e2 != clampi(tgtb[uu - 1], 1, Cn - 1));  // uu >= 127 > 0 here
    }

    // t = 0 init
    abuf[0][s1 + 2] = (s1 == 0) ? lpb[0] : (s1 == 1 ? lpb[e1] : NEGF);
    if (s2v < Sn) abuf[0][s2v + 2] = NEGF;
    if (nt < 2) { abuf[0][nt] = NEGF; abuf[1][nt] = NEGF; }
    // 2-deep emission prefetch (addresses t-invariant per thread).
    pe1_0 = lpb[Cn + e1];
    pe2_0 = lpb[Cn + e2];
    pe1_1 = lpb[(size_t)2 * Cn + e1];
    pe2_1 = lpb[(size_t)2 * Cn + e2];
  }
  __syncthreads();

  const uint32_t ONE2 = 0x3C003C00u;  // f16 (1.0, 1.0)
  const bool q4 = (dq & 4) != 0, q2 = (dq & 2) != 0, q1 = (dq & 1) != 0;

  for (int t = 1; t < L; ++t) {
    if (isden) {
      // ---------------- den step (R1-verbatim) ----------------
      const int pr = (t - 1) & 1, pw = t & 1;
      const int jw = (tid >> 3) + 32 * dq;
      const float lp_cur = lp0;
      lp0 = lp1;
      const int tpre = (t + 2 < L) ? t + 2 : L - 1;
      lp1 = lpb[(size_t)tpre * Cn + jw];  // prefetch frame t+2
      const float p = __expf(lp_cur);

      const uint4* eap = (const uint4*)(rbase0 + pr * 640);
      float a0 = 0.f, a1 = 0.f, a2 = 0.f, a3 = 0.f;
      float a4 = 0.f, a5 = 0.f, a6 = 0.f, a7 = 0.f;
      half2_t zpk = {(_Float16)0.f, (_Float16)0.f};
#define B2(x) __builtin_bit_cast(half2_t, x)
#define DOT8(idx, ev)               \
  a0 = fdot2f(E0[idx], ev, a0);     \
  a1 = fdot2f(E1[idx], ev, a1);     \
  a2 = fdot2f(E2[idx], ev, a2);     \
  a3 = fdot2f(E3[idx], ev, a3);     \
  a4 = fdot2f(E4[idx], ev, a4);     \
  a5 = fdot2f(E5[idx], ev, a5);     \
  a6 = fdot2f(E6[idx], ev, a6);     \
  a7 = fdot2f(E7[idx], ev, a7);
#define DOTQ(m4)                                                      \
  {                                                                   \
    const uint4 e4 = eap[m4];                                         \
    DOT8(4 * (m4) + 0, e4.x)                                          \
    DOT8(4 * (m4) + 1, e4.y)                                          \
    DOT8(4 * (m4) + 2, e4.z)                                          \
    DOT8(4 * (m4) + 3, e4.w)                                          \
    zpk = zpk + ((B2(e4.x) + B2(e4.y)) + (B2(e4.z) + B2(e4.w)));      \
  }
      DOTQ(0)
      DOTQ(1)
      DOTQ(2)
      DOTQ(3)
#undef DOTQ
#undef DOT8
#undef B2

      // Z = Sigma_i ea_i: chunk sum (f16 pairs) -> 8-lane DPP butterfly
      float zc = fdot2f(ONE2, __builtin_bit_cast(uint32_t, zpk), 0.f);
      zc += dpp_x1(zc);
      zc += dpp_x2(zc);
      zc += dpp_x7(zc);  // all 8 lanes of the q-group now hold Z

      // column reduce over the 8-lane q-group: give/keep halving exchange.
      float g, t0, t1, t2, t3, w0, w1, s;
      g = q4 ? a0 : a4;  t0 = (q4 ? a4 : a0) + dpp_x7(g);
      g = q4 ? a1 : a5;  t1 = (q4 ? a5 : a1) + dpp_x7(g);
      g = q4 ? a2 : a6;  t2 = (q4 ? a6 : a2) + dpp_x7(g);
      g = q4 ? a3 : a7;  t3 = (q4 ? a7 : a3) + dpp_x7(g);
      g = q2 ? t0 : t2;  w0 = (q2 ? t2 : t0) + dpp_x2(g);
      g = q2 ? t1 : t3;  w1 = (q2 ? t3 : t1) + dpp_x2(g);
      g = q1 ? w0 : w1;  s  = (q1 ? w1 : w0) + dpp_x1(g);
      // lane (u,q) now holds full s for column u+32q = jw

      const float invZ = Kn * __frcp_rn(zc);
      G -= __logf(invZ);
      *(_Float16*)(wptr0 + pw * 640) = (_Float16)(s * p * invZ);
    } else {
      // ---------------- num step (R1-verbatim) ----------------
      const int nt = tid - 256;
      const int s1 = nt;
      const float em1 = pe1_0, em2 = pe2_0;
      pe1_0 = pe1_1;
      pe2_0 = pe2_1;
      const int tpre = (t + 2 < L) ? t + 2 : L - 1;
      pe1_1 = lpb[(size_t)tpre * Cn + e1];
      pe2_1 = lpb[(size_t)tpre * Cn + e2];
      const float* A = abuf[cur];
      float* Bv = abuf[cur ^ 1];
      {
        const float x = A[s1 + 2], y = A[s1 + 1];
        const float z = k1 ? A[s1] : NEGF;
        Bv[s1 + 2] = lse3(x, y, z) + em1;
      }
      if (s2v < Sn) {
        const float x = A[s2v + 2], y = A[s2v + 1];
        const float z = k2 ? A[s2v] : NEGF;
        Bv[s2v + 2] = lse3(x, y, z) + em2;
      }
      cur ^= 1;
    }
    barrier_nodrain();  // block-scope: syncs den alpha dbuf AND num abuf dbuf
  }

  // ================= finales (one shared __syncthreads) =================
  if (isden) {
    const int pL = (L - 1) & 1;
    const char* fb = eaLDS + pL * 640;
    float e = (float)(*(const _Float16*)(fb + 80 * (tid >> 5) + 2 * (tid & 31)));
#pragma unroll
    for (int off = 32; off >= 1; off >>= 1) e += __shfl_xor(e, off, 64);
    const int lane = tid & 63, wid = tid >> 6;
    if (lane == 0) sred[wid] = e;
  }
  __syncthreads();
  if (tid == 0) {
    float ssum = (sred[0] + sred[1]) + (sred[2] + sred[3]);
    ws[Bn + b] = G + __logf(ssum);
  }
  if (tid == 256) {
    const int tl = clampi(tgt_lens[b], 1, Un);
    const int l = 2 * tl;
    const float x = abuf[cur][l + 2], y = abuf[cur][l + 1];
    const float m = fmaxf(x, y);
    ws[b] = m + __logf(__expf(x - m) + __expf(y - m));
  }
}

__global__ void finalize_kernel(const float* __restrict__ ws,
                                float* __restrict__ out) {
  const int tid = threadIdx.x;  // 64 threads, one wave
  float tot = 0.f, cnt = 0.f;
  if (tid < Bn) {
    const float tv = ws[tid] - ws[Bn + tid];  // num - DEN_SCALE*den
    const bool valid = tv > 0.5f * NEGF;
    tot = valid ? tv : 0.f;
    cnt = valid ? 1.f : 0.f;
  }
#pragma unroll
  for (int off = 32; off >= 1; off >>= 1) {
    tot += __shfl_xor(tot, off, 64);
    cnt += __shfl_xor(cnt, off, 64);
  }
  if (tid == 0) out[0] = -tot / fmaxf(cnt, 1.f);
}

extern "C" void kernel_launch(void* const* d_in, const int* in_sizes, int n_in,
                              void* d_out, int out_size, void* d_ws, size_t ws_size,
                              hipStream_t stream) {
  const float* logp = (const float*)d_in[0];
  const int* targets = (const int*)d_in[1];
  const int* in_lens = (const int*)d_in[2];
  const int* tgt_lens = (const int*)d_in[3];
  const float* trans = (const float*)d_in[4];
  const float* start = (const float*)d_in[5];
  float* ws = (float*)d_ws;
  float* out = (float*)d_out;
  (void)in_sizes; (void)n_in; (void)out_size; (void)ws_size;

  fwd_kernel<<<dim3(Bn), dim3(512), 0, stream>>>(
      logp, targets, in_lens, tgt_lens, trans, start, ws);
  finalize_kernel<<<dim3(1), dim3(64), 0, stream>>>(ws, out);
}